// Round 1
// baseline (61.638 us; speedup 1.0000x reference)
//
#include <hip/hip_runtime.h>
#include <math.h>

// Math collapse: softmax_j(sx[b,i] + sk[j] + b0) == softmax_j(sk[j])  (shift-
// invariance along the softmax axis), so attn is identical for every (b,i) and
// out[b,i,:] = sum_j softmax(sk)_j * value[j,:] is ONE 3-vector broadcast to
// all 32*512 rows. x and b are mathematically dead inputs.
//
// One launch: 64 blocks x 256 threads. Each block redundantly computes the
// 2048-point softmax+weighted-sum (key/value are 24 KB total -> L2 resident),
// then writes its 768-float slice of the 49152-float output.

__global__ __launch_bounds__(256) void attn_collapsed(
    const float* __restrict__ key,    // (2048, 3)
    const float* __restrict__ value,  // (2048, 3)
    const float* __restrict__ W,      // (1, 6): wx[0:3], wk[3:6]
    float* __restrict__ out)          // (32, 512, 3) flat = 49152 floats
{
    const int tid  = threadIdx.x;          // 0..255
    const int wave = tid >> 6;             // 4 waves of 64
    const int lane = tid & 63;

    const float wk0 = W[3], wk1 = W[4], wk2 = W[5];

    // --- scores sk[j] = key[j] . wk, 8 j's per thread ---
    float sk[8];
    float vmax = -3.4e38f;
#pragma unroll
    for (int r = 0; r < 8; ++r) {
        const int j = tid + r * 256;
        const float k0 = key[3 * j + 0];
        const float k1 = key[3 * j + 1];
        const float k2 = key[3 * j + 2];
        const float s  = fmaf(k0, wk0, fmaf(k1, wk1, k2 * wk2));
        sk[r] = s;
        vmax  = fmaxf(vmax, s);
    }

    // --- block max: 64-lane butterfly, then 4-wave LDS combine ---
#pragma unroll
    for (int m = 32; m >= 1; m >>= 1)
        vmax = fmaxf(vmax, __shfl_xor(vmax, m, 64));
    __shared__ float smax[4];
    if (lane == 0) smax[wave] = vmax;
    __syncthreads();
    const float bmax = fmaxf(fmaxf(smax[0], smax[1]), fmaxf(smax[2], smax[3]));

    // --- exp, partition function, weighted value sums ---
    float z = 0.f, a0 = 0.f, a1 = 0.f, a2 = 0.f;
#pragma unroll
    for (int r = 0; r < 8; ++r) {
        const int j = tid + r * 256;
        const float e = expf(sk[r] - bmax);
        z += e;
        a0 = fmaf(e, value[3 * j + 0], a0);
        a1 = fmaf(e, value[3 * j + 1], a1);
        a2 = fmaf(e, value[3 * j + 2], a2);
    }
#pragma unroll
    for (int m = 32; m >= 1; m >>= 1) {
        z  += __shfl_xor(z,  m, 64);
        a0 += __shfl_xor(a0, m, 64);
        a1 += __shfl_xor(a1, m, 64);
        a2 += __shfl_xor(a2, m, 64);
    }
    __shared__ float ssum[4][4];
    if (lane == 0) {
        ssum[wave][0] = z;  ssum[wave][1] = a0;
        ssum[wave][2] = a1; ssum[wave][3] = a2;
    }
    __syncthreads();
    z  = ssum[0][0] + ssum[1][0] + ssum[2][0] + ssum[3][0];
    a0 = ssum[0][1] + ssum[1][1] + ssum[2][1] + ssum[3][1];
    a1 = ssum[0][2] + ssum[1][2] + ssum[2][2] + ssum[3][2];
    a2 = ssum[0][3] + ssum[1][3] + ssum[2][3] + ssum[3][3];

    const float inv = 1.0f / z;
    const float v0 = a0 * inv, v1 = a1 * inv, v2 = a2 * inv;

    // --- broadcast write: block writes 768 consecutive floats ---
    // base is a multiple of 3, so (base+i) % 3 == i % 3.
    const int base = blockIdx.x * 768;
#pragma unroll
    for (int r = 0; r < 3; ++r) {
        const int i = tid + r * 256;
        const int d = i % 3;
        out[base + i] = (d == 0) ? v0 : ((d == 1) ? v1 : v2);
    }
}

extern "C" void kernel_launch(void* const* d_in, const int* in_sizes, int n_in,
                              void* d_out, int out_size, void* d_ws, size_t ws_size,
                              hipStream_t stream) {
    // setup_inputs order: x(0, unused), key(1), value(2), W(3), b(4, unused)
    const float* key   = (const float*)d_in[1];
    const float* value = (const float*)d_in[2];
    const float* W     = (const float*)d_in[3];
    float* out = (float*)d_out;

    // 64 blocks * 768 floats/block = 49152 = out_size
    attn_collapsed<<<dim3(64), dim3(256), 0, stream>>>(key, value, W, out);
}